// Round 1
// baseline (1400.358 us; speedup 1.0000x reference)
//
#include <hip/hip_runtime.h>
#include <hip/hip_bf16.h>

#define DEV static __device__ __forceinline__

typedef __attribute__((ext_vector_type(4))) float f32x4;
typedef __attribute__((ext_vector_type(8))) short bf16x8;

DEV ushort f2bf(float f){
  union { float f; unsigned u; } v; v.f = f;
  unsigned u = v.u;
  unsigned r = (u + 0x7FFFu + ((u >> 16) & 1u)) >> 16;
  return (ushort)r;
}
DEV float bf2f(ushort u){
  union { unsigned u; float f; } v; v.u = ((unsigned)u) << 16;
  return v.f;
}

// ---------------------------------------------------------------------------
// Transpose + cvt: W [1280,1280] f32 row-major -> WT [1280,1280] bf16 (N-major,
// K-contiguous), optionally scaled.
// ---------------------------------------------------------------------------
__global__ __launch_bounds__(256)
void transpose_cvt(const float* __restrict__ W, ushort* __restrict__ WT, float scale)
{
  __shared__ float tile[32][33];
  const int n0 = blockIdx.x * 32, k0 = blockIdx.y * 32;
  const int tx = threadIdx.x & 31, ty = threadIdx.x >> 5;
  #pragma unroll
  for (int i = 0; i < 32; i += 8)
    tile[ty + i][tx] = W[(long)(k0 + ty + i) * 1280 + n0 + tx];
  __syncthreads();
  #pragma unroll
  for (int i = 0; i < 32; i += 8)
    WT[(long)(n0 + ty + i) * 1280 + k0 + tx] = f2bf(tile[tx][ty + i] * scale);
}

// ---------------------------------------------------------------------------
// GEMM: C[M,N] (bf16) = A[M,K] @ B^T, where B is bf16 [N,K] (K-contiguous).
// A is f32 (A_IS_F32) or bf16. 128x128 tile, BK=32, 4 waves (2x2 of 64x64),
// double-buffered LDS, reg-staged global->LDS with on-the-fly f32->bf16 cvt.
// LDS layout [kb][row][8] so MFMA fragments are contiguous 16B ds_read_b128.
// ---------------------------------------------------------------------------
template<bool A_IS_F32>
__global__ __launch_bounds__(256)
void gemm_bt(const void* __restrict__ Av, const ushort* __restrict__ B,
             ushort* __restrict__ C, int M, int N, int K,
             long sA, long sB, long sC)
{
  const float*  Af = (const float*)Av;
  const ushort* Ah = (const ushort*)Av;
  __shared__ __align__(16) ushort As[2][4][128][8];
  __shared__ __align__(16) ushort Bs[2][4][128][8];

  const int tid  = threadIdx.x;
  const int lane = tid & 63;
  const int wid  = tid >> 6;
  const int wr = wid >> 1, wc = wid & 1;
  const int bm = blockIdx.y * 128, bn = blockIdx.x * 128;
  const long Ab = (long)blockIdx.z * sA;
  const long Bb = (long)blockIdx.z * sB;
  const long Cb = (long)blockIdx.z * sC;

  f32x4 acc[4][4];
  #pragma unroll
  for (int i = 0; i < 4; i++)
    #pragma unroll
    for (int j = 0; j < 4; j++)
      acc[i][j] = (f32x4){0.f, 0.f, 0.f, 0.f};

  float4 aregf[4];
  uint4  aregh[2];
  uint4  bregh[2];

  auto LOADG = [&](int k0) {
    if constexpr (A_IS_F32) {
      #pragma unroll
      for (int i = 0; i < 4; i++) {
        int c = tid + i * 256;
        int r = c >> 3, kc = (c & 7) * 4;
        aregf[i] = *(const float4*)(Af + Ab + (long)(bm + r) * K + (k0 + kc));
      }
    } else {
      #pragma unroll
      for (int i = 0; i < 2; i++) {
        int c = tid + i * 256;
        int r = c >> 2, kc = (c & 3) * 8;
        aregh[i] = *(const uint4*)(Ah + Ab + (long)(bm + r) * K + (k0 + kc));
      }
    }
    #pragma unroll
    for (int i = 0; i < 2; i++) {
      int c = tid + i * 256;
      int r = c >> 2, kc = (c & 3) * 8;
      bregh[i] = *(const uint4*)(B + Bb + (long)(bn + r) * K + (k0 + kc));
    }
  };

  auto WRITELDS = [&](int buf) {
    if constexpr (A_IS_F32) {
      #pragma unroll
      for (int i = 0; i < 4; i++) {
        int c = tid + i * 256;
        int r = c >> 3;
        int kb = (c & 7) >> 1, ko = (c & 1) * 4;
        ushort4 u;
        u.x = f2bf(aregf[i].x); u.y = f2bf(aregf[i].y);
        u.z = f2bf(aregf[i].z); u.w = f2bf(aregf[i].w);
        *(ushort4*)&As[buf][kb][r][ko] = u;
      }
    } else {
      #pragma unroll
      for (int i = 0; i < 2; i++) {
        int c = tid + i * 256;
        int r = c >> 2, kb = c & 3;
        *(uint4*)&As[buf][kb][r][0] = aregh[i];
      }
    }
    #pragma unroll
    for (int i = 0; i < 2; i++) {
      int c = tid + i * 256;
      int r = c >> 2, kb = c & 3;
      *(uint4*)&Bs[buf][kb][r][0] = bregh[i];
    }
  };

  LOADG(0);
  WRITELDS(0);
  __syncthreads();

  const int NT = K >> 5;
  for (int t = 0; t < NT; ++t) {
    const int cur = t & 1;
    if (t + 1 < NT) LOADG((t + 1) * 32);

    bf16x8 af[4], bfr[4];
    #pragma unroll
    for (int mi = 0; mi < 4; mi++)
      af[mi] = *(const bf16x8*)&As[cur][lane >> 4][wr * 64 + mi * 16 + (lane & 15)][0];
    #pragma unroll
    for (int ni = 0; ni < 4; ni++)
      bfr[ni] = *(const bf16x8*)&Bs[cur][lane >> 4][wc * 64 + ni * 16 + (lane & 15)][0];
    #pragma unroll
    for (int mi = 0; mi < 4; mi++)
      #pragma unroll
      for (int ni = 0; ni < 4; ni++)
        acc[mi][ni] = __builtin_amdgcn_mfma_f32_16x16x32_bf16(af[mi], bfr[ni], acc[mi][ni], 0, 0, 0);

    __syncthreads();
    if (t + 1 < NT) WRITELDS(cur ^ 1);
    __syncthreads();
  }

  // Epilogue: C/D layout col=lane&15, row=(lane>>4)*4+reg (m89-verified).
  #pragma unroll
  for (int mi = 0; mi < 4; mi++)
    #pragma unroll
    for (int ni = 0; ni < 4; ni++)
      #pragma unroll
      for (int r = 0; r < 4; r++) {
        int row = bm + wr * 64 + mi * 16 + (lane >> 4) * 4 + r;
        int col = bn + wc * 64 + ni * 16 + (lane & 15);
        C[Cb + (long)row * N + col] = f2bf(acc[mi][ni][r]);
      }
}

// ---------------------------------------------------------------------------
// Softmax over c (2048) per (b,s) row of S (bf16), accumulate column sums
// wsum[b,c] = sum_s softmax(S[b,s,:])[c].  One wave per row-group of 8 rows;
// the row lives in 32 registers/lane; per-lane c-slots accumulated in regs,
// one atomicAdd pass at the end.
// ---------------------------------------------------------------------------
__global__ __launch_bounds__(256)
void softmax_wsum(const ushort* __restrict__ S, float* __restrict__ wsum)
{
  const int b = blockIdx.x;
  const int s0 = blockIdx.y * 32;
  const int lane = threadIdx.x & 63;
  const int wave = threadIdx.x >> 6;
  const ushort* Sb = S + (((long)b * 1024) + s0 + wave * 8) * 2048;

  float acc[32];
  #pragma unroll
  for (int i = 0; i < 32; i++) acc[i] = 0.f;

  for (int r = 0; r < 8; r++) {
    const ushort* row = Sb + (long)r * 2048;
    float v[32];
    #pragma unroll
    for (int i = 0; i < 4; i++) {
      uint4 u = *(const uint4*)(row + i * 512 + lane * 8);
      const ushort* up = (const ushort*)&u;
      #pragma unroll
      for (int j = 0; j < 8; j++) v[i * 8 + j] = bf2f(up[j]);
    }
    float m = v[0];
    #pragma unroll
    for (int i = 1; i < 32; i++) m = fmaxf(m, v[i]);
    #pragma unroll
    for (int o = 1; o < 64; o <<= 1) m = fmaxf(m, __shfl_xor(m, o));
    float ssum = 0.f;
    #pragma unroll
    for (int i = 0; i < 32; i++) { v[i] = __expf(v[i] - m); ssum += v[i]; }
    #pragma unroll
    for (int o = 1; o < 64; o <<= 1) ssum += __shfl_xor(ssum, o);
    float inv = 1.f / ssum;
    #pragma unroll
    for (int i = 0; i < 32; i++) acc[i] += v[i] * inv;
  }

  float* wb = wsum + b * 2048;
  #pragma unroll
  for (int i = 0; i < 4; i++)
    #pragma unroll
    for (int j = 0; j < 8; j++)
      atomicAdd(&wb[i * 512 + lane * 8 + j], acc[i * 8 + j]);
}

// t[b,d] = sum_c wsum[b,c] * cyclase[b,c,d]
__global__ __launch_bounds__(256)
void wcyc_kernel(const float* __restrict__ cyc, const float* __restrict__ wsum,
                 float* __restrict__ t)
{
  const int b = blockIdx.x;
  const int d = blockIdx.y * 256 + threadIdx.x;
  const int c0 = blockIdx.z * 256;
  const float* cb = cyc + ((long)b * 2048 + c0) * 1280 + d;
  const float* wb = wsum + b * 2048 + c0;
  float a = 0.f;
  for (int c = 0; c < 256; c++) a += wb[c] * cb[(long)c * 1280];
  atomicAdd(&t[b * 1280 + d], a);
}

// xcat[b, 1280+d] = mean_s substrate[b,s,d]
__global__ __launch_bounds__(256)
void submean_kernel(const float* __restrict__ sub, float* __restrict__ xcat)
{
  const int b = blockIdx.x;
  const int d = blockIdx.y * 256 + threadIdx.x;
  const int s0 = blockIdx.z * 256;
  const float* sb = sub + ((long)b * 1024 + s0) * 1280 + d;
  float a = 0.f;
  for (int s = 0; s < 256; s++) a += sb[(long)s * 1280];
  atomicAdd(&xcat[b * 2560 + 1280 + d], a * (1.f / 1024.f));
}

// xcat[b, dp] = (1/1024) * sum_d t[b,d] * Wv[d,dp]
__global__ __launch_bounds__(256)
void xv_kernel(const float* __restrict__ t, const float* __restrict__ Wv,
               float* __restrict__ xcat)
{
  const int b = blockIdx.y;
  const int dp = blockIdx.x * 256 + threadIdx.x;
  __shared__ float tl[1280];
  for (int i = threadIdx.x; i < 1280; i += 256) tl[i] = t[b * 1280 + i];
  __syncthreads();
  float a = 0.f;
  for (int d = 0; d < 1280; d++) a += tl[d] * Wv[(long)d * 1280 + dp];
  xcat[b * 2560 + dp] = a * (1.f / 1024.f);
}

// h1 = relu(xcat @ W1 + b1)
__global__ __launch_bounds__(256)
void mlp1_kernel(const float* __restrict__ xcat, const float* __restrict__ W1,
                 const float* __restrict__ b1, float* __restrict__ h1)
{
  const int b = blockIdx.y;
  const int j = blockIdx.x * 256 + threadIdx.x;
  __shared__ float xl[2560];
  for (int i = threadIdx.x; i < 2560; i += 256) xl[i] = xcat[b * 2560 + i];
  __syncthreads();
  float a = b1[j];
  for (int d = 0; d < 2560; d++) a += xl[d] * W1[(long)d * 512 + j];
  h1[b * 512 + j] = fmaxf(a, 0.f);
}

// h2 = relu(h1 @ W2 + b2); out = sigmoid(h2 @ W3 + b3)
__global__ __launch_bounds__(64)
void mlp23_kernel(const float* __restrict__ h1, const float* __restrict__ W2,
                  const float* __restrict__ b2, const float* __restrict__ W3,
                  const float* __restrict__ b3, float* __restrict__ out)
{
  const int b = blockIdx.x;
  const int j = threadIdx.x;  // 64 threads = 1 wave
  __shared__ float hl[512];
  for (int i = j; i < 512; i += 64) hl[i] = h1[b * 512 + i];
  __syncthreads();
  float a = b2[j];
  for (int d = 0; d < 512; d++) a += hl[d] * W2[d * 64 + j];
  a = fmaxf(a, 0.f);
  float p = a * W3[j];
  #pragma unroll
  for (int o = 1; o < 64; o <<= 1) p += __shfl_xor(p, o);
  if (j == 0) out[b] = 1.f / (1.f + __expf(-(p + b3[0])));
}

extern "C" void kernel_launch(void* const* d_in, const int* in_sizes, int n_in,
                              void* d_out, int out_size, void* d_ws, size_t ws_size,
                              hipStream_t stream)
{
  const float* cyclase   = (const float*)d_in[0];
  const float* substrate = (const float*)d_in[1];
  // d_in[2], d_in[3] are masks; the reference's masking is a no-op (replicated bug).
  const float* Wq = (const float*)d_in[4];
  const float* Wk = (const float*)d_in[5];
  const float* Wv = (const float*)d_in[6];
  const float* W1 = (const float*)d_in[7];
  const float* b1 = (const float*)d_in[8];
  const float* W2 = (const float*)d_in[9];
  const float* b2 = (const float*)d_in[10];
  const float* W3 = (const float*)d_in[11];
  const float* b3 = (const float*)d_in[12];
  float* out = (float*)d_out;
  (void)in_sizes; (void)n_in; (void)out_size; (void)ws_size;

  char* ws = (char*)d_ws;
  size_t off = 0;
  auto alloc = [&](size_t bytes) {
    void* p = ws + off;
    off += (bytes + 255) & ~(size_t)255;
    return p;
  };
  ushort* Q    = (ushort*)alloc(16384ull * 1280 * 2);   // 41.9 MB
  ushort* Kp   = (ushort*)alloc(32768ull * 1280 * 2);   // 83.9 MB
  ushort* S    = (ushort*)alloc(16ull * 1024 * 2048 * 2); // 67.1 MB
  ushort* WqT  = (ushort*)alloc(1280ull * 1280 * 2);
  ushort* WkT  = (ushort*)alloc(1280ull * 1280 * 2);
  float*  wsum = (float*)alloc(16 * 2048 * 4);
  float*  tbuf = (float*)alloc(16 * 1280 * 4);
  float*  xcat = (float*)alloc(16 * 2560 * 4);
  float*  h1   = (float*)alloc(16 * 512 * 4);

  hipMemsetAsync(wsum, 0, 16 * 2048 * 4, stream);
  hipMemsetAsync(tbuf, 0, 16 * 1280 * 4, stream);
  hipMemsetAsync(xcat, 0, 16 * 2560 * 4, stream);

  // Fold 1/sqrt(1280) into WqT so the scores GEMM is pure.
  transpose_cvt<<<dim3(40, 40), 256, 0, stream>>>(Wq, WqT, 0.02795084971874737f);
  transpose_cvt<<<dim3(40, 40), 256, 0, stream>>>(Wk, WkT, 1.0f);

  // Q = (substrate @ Wq) * scale  : [16384,1280] bf16
  gemm_bt<true><<<dim3(10, 128, 1), 256, 0, stream>>>(substrate, WqT, Q,
      16384, 1280, 1280, 0, 0, 0);
  // Kp = cyclase @ Wk : [32768,1280] bf16
  gemm_bt<true><<<dim3(10, 256, 1), 256, 0, stream>>>(cyclase, WkT, Kp,
      32768, 1280, 1280, 0, 0, 0);
  // S[b] = Q[b] @ Kp[b]^T : [16,1024,2048] bf16
  gemm_bt<false><<<dim3(16, 8, 16), 256, 0, stream>>>(Q, Kp, S,
      1024, 2048, 1280, 1024l * 1280, 2048l * 1280, 1024l * 2048);

  softmax_wsum<<<dim3(16, 32), 256, 0, stream>>>(S, wsum);

  wcyc_kernel<<<dim3(16, 5, 8), 256, 0, stream>>>(cyclase, wsum, tbuf);
  submean_kernel<<<dim3(16, 5, 4), 256, 0, stream>>>(substrate, xcat);
  xv_kernel<<<dim3(5, 16), 256, 0, stream>>>(tbuf, Wv, xcat);
  mlp1_kernel<<<dim3(2, 16), 256, 0, stream>>>(xcat, W1, b1, h1);
  mlp23_kernel<<<16, 64, 0, stream>>>(h1, W2, b2, W3, b3, out);
}

// Round 2
// 814.767 us; speedup vs baseline: 1.7187x; 1.7187x over previous
//
#include <hip/hip_runtime.h>
#include <hip/hip_bf16.h>

#define DEV static __device__ __forceinline__

typedef __attribute__((ext_vector_type(4))) float f32x4;
typedef __attribute__((ext_vector_type(8))) short bf16x8;

DEV ushort f2bf(float f){
  union { float f; unsigned u; } v; v.f = f;
  unsigned u = v.u;
  return (ushort)((u + 0x7FFFu + ((u >> 16) & 1u)) >> 16);
}
DEV float bf2f(ushort u){
  union { unsigned u; float f; } v; v.u = ((unsigned)u) << 16;
  return v.f;
}

// async global->LDS, 16B per lane; LDS dest is wave-uniform base + lane*16.
DEV void gload16(const ushort* g, ushort* l) {
  __builtin_amdgcn_global_load_lds(
      (const __attribute__((address_space(1))) unsigned*)g,
      (__attribute__((address_space(3))) unsigned*)l, 16, 0, 0);
}

// ---------------------------------------------------------------------------
// Elementwise f32 -> bf16 (8 elems/thread, grid-stride).
// ---------------------------------------------------------------------------
__global__ __launch_bounds__(256)
void cvt_bf16(const float* __restrict__ src, ushort* __restrict__ dst, long n8)
{
  const long stride = (long)gridDim.x * 256;
  for (long i = (long)blockIdx.x * 256 + threadIdx.x; i < n8; i += stride) {
    const float4 a = *(const float4*)(src + i * 8);
    const float4 b = *(const float4*)(src + i * 8 + 4);
    union { ushort u[8]; uint4 v; } pk;
    pk.u[0] = f2bf(a.x); pk.u[1] = f2bf(a.y); pk.u[2] = f2bf(a.z); pk.u[3] = f2bf(a.w);
    pk.u[4] = f2bf(b.x); pk.u[5] = f2bf(b.y); pk.u[6] = f2bf(b.z); pk.u[7] = f2bf(b.w);
    *(uint4*)(dst + i * 8) = pk.v;
  }
}

// ---------------------------------------------------------------------------
// bf16 GEMM: C[M,N] = (A[M,K] @ B^T) * scale, B is [N,K] K-contiguous, all bf16.
// 128x128 tile, BK=32, 4 waves (2x2 of 64x64), double-buffered LDS filled via
// global_load_lds (16B/lane). LDS layout [kb][row][8] = contiguous MFMA frags.
// Grid is 1D; m204 bijective XCD-chunk swizzle; BY_FAST picks traversal order.
// ---------------------------------------------------------------------------
template<bool BY_FAST>
__global__ __launch_bounds__(256)
void gemm16(const ushort* __restrict__ A, const ushort* __restrict__ B,
            ushort* __restrict__ C, int K, int N, int nbx, int nby,
            long sA, long sB, long sC, float scale)
{
  __shared__ __align__(16) ushort As[2][4][128][8];
  __shared__ __align__(16) ushort Bs[2][4][128][8];

  const int tid = threadIdx.x, lane = tid & 63, wid = tid >> 6;
  const int wr = wid >> 1, wc = wid & 1;

  // bijective XCD-chunk swizzle (m204): XCD x owns a contiguous id range.
  const int nwg = gridDim.x;
  const int q = nwg >> 3, r = nwg & 7;
  const int xcd = blockIdx.x & 7, lid = blockIdx.x >> 3;
  const int id = (xcd < r ? xcd * (q + 1) : r * (q + 1) + (xcd - r) * q) + lid;
  const int per = nbx * nby;
  const int z = id / per, rem = id - z * per;
  const int bx = BY_FAST ? rem / nby : rem % nbx;
  const int by = BY_FAST ? rem % nby : rem / nbx;

  const int bm = by * 128, bn = bx * 128;
  const long Ab = (long)z * sA, Bb = (long)z * sB, Cb = (long)z * sC;

  f32x4 acc[4][4];
  #pragma unroll
  for (int i = 0; i < 4; i++)
    #pragma unroll
    for (int j = 0; j < 4; j++)
      acc[i][j] = (f32x4){0.f, 0.f, 0.f, 0.f};

  // 16 chunks of 1KB per buffer-fill (8 A + 8 B), 4 per wave.
  // chunk c -> kb = (c&7)>>1, row-half = c&1; dest byte = c*1024 (+ lane*16 by HW).
  auto STAGE = [&](int buf, int k0) {
    #pragma unroll
    for (int i = 0; i < 4; i++) {
      const int c = wid * 4 + i;
      const int kb = (c & 7) >> 1, rh = c & 1;
      if (c < 8)
        gload16(A + Ab + (long)(bm + rh * 64 + lane) * K + k0 + kb * 8,
                &As[buf][kb][rh * 64][0]);
      else
        gload16(B + Bb + (long)(bn + rh * 64 + lane) * K + k0 + kb * 8,
                &Bs[buf][kb][rh * 64][0]);
    }
  };

  STAGE(0, 0);
  __syncthreads();

  const int NT = K >> 5;
  for (int t = 0; t < NT; ++t) {
    const int cur = t & 1;
    if (t + 1 < NT) STAGE(cur ^ 1, (t + 1) * 32);

    bf16x8 af[4], bf[4];
    #pragma unroll
    for (int mi = 0; mi < 4; mi++)
      af[mi] = *(const bf16x8*)&As[cur][lane >> 4][wr * 64 + mi * 16 + (lane & 15)][0];
    #pragma unroll
    for (int ni = 0; ni < 4; ni++)
      bf[ni] = *(const bf16x8*)&Bs[cur][lane >> 4][wc * 64 + ni * 16 + (lane & 15)][0];
    #pragma unroll
    for (int mi = 0; mi < 4; mi++)
      #pragma unroll
      for (int ni = 0; ni < 4; ni++)
        acc[mi][ni] = __builtin_amdgcn_mfma_f32_16x16x32_bf16(af[mi], bf[ni], acc[mi][ni], 0, 0, 0);

    __syncthreads();  // drains vmcnt -> buf cur^1 ready; protects cur from t+1's STAGE
  }

  // C/D layout: col=lane&15, row=(lane>>4)*4+reg (m89-verified).
  #pragma unroll
  for (int mi = 0; mi < 4; mi++)
    #pragma unroll
    for (int ni = 0; ni < 4; ni++)
      #pragma unroll
      for (int r2 = 0; r2 < 4; r2++) {
        const int row = bm + wr * 64 + mi * 16 + (lane >> 4) * 4 + r2;
        const int col = bn + wc * 64 + ni * 16 + (lane & 15);
        C[Cb + (long)row * N + col] = f2bf(acc[mi][ni][r2] * scale);
      }
}

// ---------------------------------------------------------------------------
// Softmax over c per (b,s) row of S (bf16); accumulate wsum[b,c] = sum_s w[s,c].
// One wave per 8 rows; row in 32 regs/lane; one atomicAdd pass at the end.
// ---------------------------------------------------------------------------
__global__ __launch_bounds__(256)
void softmax_wsum(const ushort* __restrict__ S, float* __restrict__ wsum)
{
  const int b = blockIdx.x;
  const int s0 = blockIdx.y * 32;
  const int lane = threadIdx.x & 63;
  const int wave = threadIdx.x >> 6;
  const ushort* Sb = S + (((long)b * 1024) + s0 + wave * 8) * 2048;

  float acc[32];
  #pragma unroll
  for (int i = 0; i < 32; i++) acc[i] = 0.f;

  for (int r = 0; r < 8; r++) {
    const ushort* row = Sb + (long)r * 2048;
    float v[32];
    #pragma unroll
    for (int i = 0; i < 4; i++) {
      uint4 u = *(const uint4*)(row + i * 512 + lane * 8);
      const ushort* up = (const ushort*)&u;
      #pragma unroll
      for (int j = 0; j < 8; j++) v[i * 8 + j] = bf2f(up[j]);
    }
    float m = v[0];
    #pragma unroll
    for (int i = 1; i < 32; i++) m = fmaxf(m, v[i]);
    #pragma unroll
    for (int o = 1; o < 64; o <<= 1) m = fmaxf(m, __shfl_xor(m, o));
    float ssum = 0.f;
    #pragma unroll
    for (int i = 0; i < 32; i++) { v[i] = __expf(v[i] - m); ssum += v[i]; }
    #pragma unroll
    for (int o = 1; o < 64; o <<= 1) ssum += __shfl_xor(ssum, o);
    const float inv = 1.f / ssum;
    #pragma unroll
    for (int i = 0; i < 32; i++) acc[i] += v[i] * inv;
  }

  float* wb = wsum + b * 2048;
  #pragma unroll
  for (int i = 0; i < 4; i++)
    #pragma unroll
    for (int j = 0; j < 8; j++)
      atomicAdd(&wb[i * 512 + lane * 8 + j], acc[i * 8 + j]);
}

// t[b,d] = sum_c wsum[b,c] * cyc16[b,c,d]
__global__ __launch_bounds__(256)
void wcyc_kernel(const ushort* __restrict__ cyc, const float* __restrict__ wsum,
                 float* __restrict__ t)
{
  const int b = blockIdx.x;
  const int d = blockIdx.y * 256 + threadIdx.x;
  const int c0 = blockIdx.z * 256;
  const ushort* cb = cyc + ((long)b * 2048 + c0) * 1280 + d;
  const float* wb = wsum + b * 2048 + c0;
  float a = 0.f;
  for (int c = 0; c < 256; c++) a += wb[c] * bf2f(cb[(long)c * 1280]);
  atomicAdd(&t[b * 1280 + d], a);
}

// xcat[b, 1280+d] = mean_s sub16[b,s,d]
__global__ __launch_bounds__(256)
void submean_kernel(const ushort* __restrict__ sub, float* __restrict__ xcat)
{
  const int b = blockIdx.x;
  const int d = blockIdx.y * 256 + threadIdx.x;
  const int s0 = blockIdx.z * 256;
  const ushort* sb = sub + ((long)b * 1024 + s0) * 1280 + d;
  float a = 0.f;
  for (int s = 0; s < 256; s++) a += bf2f(sb[(long)s * 1280]);
  atomicAdd(&xcat[b * 2560 + 1280 + d], a * (1.f / 1024.f));
}

// xcat[b, dp] = (1/1024) * sum_d t[b,d] * Wv[d,dp]
__global__ __launch_bounds__(256)
void xv_kernel(const float* __restrict__ t, const float* __restrict__ Wv,
               float* __restrict__ xcat)
{
  const int b = blockIdx.y;
  const int dp = blockIdx.x * 256 + threadIdx.x;
  __shared__ float tl[1280];
  for (int i = threadIdx.x; i < 1280; i += 256) tl[i] = t[b * 1280 + i];
  __syncthreads();
  float a = 0.f;
  for (int d = 0; d < 1280; d++) a += tl[d] * Wv[(long)d * 1280 + dp];
  xcat[b * 2560 + dp] = a * (1.f / 1024.f);
}

// h1 = relu(xcat @ W1 + b1)
__global__ __launch_bounds__(256)
void mlp1_kernel(const float* __restrict__ xcat, const float* __restrict__ W1,
                 const float* __restrict__ b1, float* __restrict__ h1)
{
  const int b = blockIdx.y;
  const int j = blockIdx.x * 256 + threadIdx.x;
  __shared__ float xl[2560];
  for (int i = threadIdx.x; i < 2560; i += 256) xl[i] = xcat[b * 2560 + i];
  __syncthreads();
  float a = b1[j];
  for (int d = 0; d < 2560; d++) a += xl[d] * W1[(long)d * 512 + j];
  h1[b * 512 + j] = fmaxf(a, 0.f);
}

// h2 = relu(h1 @ W2 + b2); out = sigmoid(h2 @ W3 + b3)
__global__ __launch_bounds__(64)
void mlp23_kernel(const float* __restrict__ h1, const float* __restrict__ W2,
                  const float* __restrict__ b2, const float* __restrict__ W3,
                  const float* __restrict__ b3, float* __restrict__ out)
{
  const int b = blockIdx.x;
  const int j = threadIdx.x;  // 64 threads = 1 wave
  __shared__ float hl[512];
  for (int i = j; i < 512; i += 64) hl[i] = h1[b * 512 + i];
  __syncthreads();
  float a = b2[j];
  for (int d = 0; d < 512; d++) a += hl[d] * W2[d * 64 + j];
  a = fmaxf(a, 0.f);
  float p = a * W3[j];
  #pragma unroll
  for (int o = 1; o < 64; o <<= 1) p += __shfl_xor(p, o);
  if (j == 0) out[b] = 1.f / (1.f + __expf(-(p + b3[0])));
}

extern "C" void kernel_launch(void* const* d_in, const int* in_sizes, int n_in,
                              void* d_out, int out_size, void* d_ws, size_t ws_size,
                              hipStream_t stream)
{
  const float* cyclase   = (const float*)d_in[0];
  const float* substrate = (const float*)d_in[1];
  // d_in[2], d_in[3]: masks — reference's masking is a no-op (replicated bug).
  const float* Wq = (const float*)d_in[4];
  const float* Wk = (const float*)d_in[5];
  const float* Wv = (const float*)d_in[6];
  const float* W1 = (const float*)d_in[7];
  const float* b1 = (const float*)d_in[8];
  const float* W2 = (const float*)d_in[9];
  const float* b2 = (const float*)d_in[10];
  const float* W3 = (const float*)d_in[11];
  const float* b3 = (const float*)d_in[12];
  float* out = (float*)d_out;
  (void)in_sizes; (void)n_in; (void)out_size; (void)ws_size;

  // Workspace layout (with lifetime-based aliasing; total ~193.4 MB):
  //   [0, 84M)            cyc16                      (cvt .. wcyc)
  //   [84M, 151.2M)       sub16(42M) + Mkq(3.3M)  -> S(67.1M) after both dead
  //   [151.2M, 193.1M)    Wq16(3.3M)+Wk16(3.3M)   -> T1(42M) after Mkq-gemm
  //   [193.1M, ...)       wsum/tbuf/xcat/h1
  char* ws = (char*)d_ws;
  ushort* cyc16 = (ushort*)ws;
  char*   base2 = ws + 83886080;
  ushort* sub16 = (ushort*)base2;
  ushort* Mkq   = (ushort*)(base2 + 41943040);
  ushort* S     = (ushort*)base2;
  char*   base3 = base2 + 67108864;
  ushort* T1    = (ushort*)base3;
  ushort* Wq16  = (ushort*)base3;
  ushort* Wk16  = (ushort*)(base3 + 3276800);
  char*   base4 = base3 + 41943040;
  float* wsum = (float*)base4;
  float* tbuf = (float*)(base4 + 131072);
  float* xcat = (float*)(base4 + 131072 + 81920);
  float* h1   = (float*)(base4 + 131072 + 81920 + 163840);

  hipMemsetAsync(wsum, 0, 16 * 2048 * 4, stream);
  hipMemsetAsync(tbuf, 0, 16 * 1280 * 4, stream);
  hipMemsetAsync(xcat, 0, 16 * 2560 * 4, stream);

  cvt_bf16<<<200, 256, 0, stream>>>(Wq, Wq16, 1280l * 1280 / 8);
  cvt_bf16<<<200, 256, 0, stream>>>(Wk, Wk16, 1280l * 1280 / 8);
  cvt_bf16<<<2048, 256, 0, stream>>>(substrate, sub16, 16l * 1024 * 1280 / 8);
  cvt_bf16<<<2048, 256, 0, stream>>>(cyclase, cyc16, 16l * 2048 * 1280 / 8);

  // Mkq = Wk @ Wq^T * (1/sqrt(1280))  [d',d]  — kills the K-projection GEMM.
  gemm16<false><<<100, 256, 0, stream>>>(Wk16, Wq16, Mkq,
      1280, 1280, 10, 10, 0, 0, 0, 0.02795084971874737f);

  submean_kernel<<<dim3(16, 5, 4), 256, 0, stream>>>(sub16, xcat);

  // T1 = sub16 @ Mkq^T  [16384,1280]   (bx-fast: A-tile stays hot per XCD)
  gemm16<false><<<1280, 256, 0, stream>>>(sub16, Mkq, T1,
      1280, 1280, 10, 128, 0, 0, 0, 1.0f);

  // S[b] = T1[b] @ cyc16[b]^T  [16,1024,2048]  (by-fast: T1[b] L2-resident)
  gemm16<true><<<2048, 256, 0, stream>>>(T1, cyc16, S,
      1280, 2048, 16, 8, 1024l * 1280, 2048l * 1280, 1024l * 2048, 1.0f);

  softmax_wsum<<<dim3(16, 32), 256, 0, stream>>>(S, wsum);
  wcyc_kernel<<<dim3(16, 5, 8), 256, 0, stream>>>(cyc16, wsum, tbuf);
  xv_kernel<<<dim3(5, 16), 256, 0, stream>>>(tbuf, Wv, xcat);
  mlp1_kernel<<<dim3(2, 16), 256, 0, stream>>>(xcat, W1, b1, h1);
  mlp23_kernel<<<16, 64, 0, stream>>>(h1, W2, b2, W3, b3, out);
}

// Round 3
// 720.043 us; speedup vs baseline: 1.9448x; 1.1316x over previous
//
#include <hip/hip_runtime.h>
#include <hip/hip_bf16.h>

#define DEV static __device__ __forceinline__

typedef __attribute__((ext_vector_type(4))) float f32x4;
typedef __attribute__((ext_vector_type(8))) short bf16x8;

DEV ushort f2bf(float f){
  union { float f; unsigned u; } v; v.f = f;
  return (ushort)((v.u + 0x7FFFu + ((v.u >> 16) & 1u)) >> 16);
}
DEV float bf2f(ushort u){
  union { unsigned u; float f; } v; v.u = ((unsigned)u) << 16;
  return v.f;
}

// async global->LDS, 16B per lane; LDS dest is wave-uniform base + lane*16.
DEV void gload16(const ushort* g, ushort* l) {
  __builtin_amdgcn_global_load_lds(
      (const __attribute__((address_space(1))) unsigned*)g,
      (__attribute__((address_space(3))) unsigned*)l, 16, 0, 0);
}

// ---------------------------------------------------------------------------
// Elementwise f32 -> bf16 (8 elems/thread, grid-stride).
// ---------------------------------------------------------------------------
__global__ __launch_bounds__(256)
void cvt_bf16(const float* __restrict__ src, ushort* __restrict__ dst, long n8)
{
  const long stride = (long)gridDim.x * 256;
  for (long i = (long)blockIdx.x * 256 + threadIdx.x; i < n8; i += stride) {
    const float4 a = *(const float4*)(src + i * 8);
    const float4 b = *(const float4*)(src + i * 8 + 4);
    union { ushort u[8]; uint4 v; } pk;
    pk.u[0] = f2bf(a.x); pk.u[1] = f2bf(a.y); pk.u[2] = f2bf(a.z); pk.u[3] = f2bf(a.w);
    pk.u[4] = f2bf(b.x); pk.u[5] = f2bf(b.y); pk.u[6] = f2bf(b.z); pk.u[7] = f2bf(b.w);
    *(uint4*)(dst + i * 8) = pk.v;
  }
}

// ---------------------------------------------------------------------------
// bf16 GEMM, deep-pipelined ring: C[M,N] = (A[M,K] @ B^T)*scale, B is [N,K]
// K-contiguous. 256x256 tile, BK=32, 8 waves (2x4, each 128x64 of C), ring of
// 3 LDS buffers (96 KiB) filled by global_load_lds (16B/lane). Counted
// s_waitcnt vmcnt(4) — loads stay in flight across barriers (T3/T4); never a
// vmcnt(0) drain in the main loop. LDS subtiling [kb][row][8] is linear for
// the DMA AND conflict-free for ds_read_b128 (measured 0 conflicts in r2).
// One s_barrier per K-tile; explicit lgkmcnt(0) before it so pending ds_reads
// can't race the next stage's DMA writes. Requires K/32 >= 2.
// ---------------------------------------------------------------------------
template<bool BY_FAST>
__global__ __launch_bounds__(512, 2)
void gemm_ring(const ushort* __restrict__ A, const ushort* __restrict__ B,
               ushort* __restrict__ C, int K, int N, int nbx, int nby,
               long sA, long sB, long sC, float scale)
{
  __shared__ __align__(16) ushort As[3][4][256][8];  // 48 KiB
  __shared__ __align__(16) ushort Bs[3][4][256][8];  // 48 KiB

  const int tid = threadIdx.x, lane = tid & 63, wid = tid >> 6;
  const int wr = wid >> 2, wc = wid & 3;  // 2 x 4 waves

  // bijective XCD-chunk swizzle (m204)
  const int nwg = gridDim.x;
  const int q = nwg >> 3, r = nwg & 7;
  const int xcd = blockIdx.x & 7, lid = blockIdx.x >> 3;
  const int id = (xcd < r ? xcd * (q + 1) : r * (q + 1) + (xcd - r) * q) + lid;
  const int per = nbx * nby;
  const int z = id / per, rem = id - z * per;
  const int bx = BY_FAST ? rem / nby : rem % nbx;
  const int by = BY_FAST ? rem % nby : rem / nbx;

  const int bm = by * 256, bn = bx * 256;
  const long Ab = (long)z * sA, Bb = (long)z * sB, Cb = (long)z * sC;

  f32x4 acc[8][4];
  #pragma unroll
  for (int i = 0; i < 8; i++)
    #pragma unroll
    for (int j = 0; j < 4; j++)
      acc[i][j] = (f32x4){0.f, 0.f, 0.f, 0.f};

  // 16 A-chunks + 16 B-chunks of 1KB per tile; wave w stages chunks {2w,2w+1}
  // of each. chunk c: kb = c>>2, row-quarter rq = c&3. 4 loads/wave/tile.
  auto STAGE = [&](int buf, int k0) {
    #pragma unroll
    for (int j = 0; j < 2; j++) {
      const int c = wid * 2 + j, kb = c >> 2, rq = c & 3;
      gload16(A + Ab + (long)(bm + rq * 64 + lane) * K + k0 + kb * 8,
              &As[buf][kb][rq * 64][0]);
    }
    #pragma unroll
    for (int j = 0; j < 2; j++) {
      const int c = wid * 2 + j, kb = c >> 2, rq = c & 3;
      gload16(B + Bb + (long)(bn + rq * 64 + lane) * K + k0 + kb * 8,
              &Bs[buf][kb][rq * 64][0]);
    }
  };

  const int NT = K >> 5;  // >= 2 required
  STAGE(0, 0);
  STAGE(1, 32);

  for (int t = 0; t < NT; ++t) {
    // my ds_reads done (cheap: already consumed by MFMAs) -> safe to cross barrier
    asm volatile("s_waitcnt lgkmcnt(0)" ::: "memory");
    // counted wait: oldest 4 loads = tile t fully issued-and-landed for THIS
    // wave; barrier below extends that to all waves. Never drains the queue.
    if (t + 1 < NT) asm volatile("s_waitcnt vmcnt(4)" ::: "memory");
    else            asm volatile("s_waitcnt vmcnt(0)" ::: "memory");
    __builtin_amdgcn_s_barrier();
    asm volatile("" ::: "memory");
    // stage tile t+2 into buf (t+2)%3 = (t-1)%3: its last reader was iter t-1,
    // and everyone passed this iteration's barrier after finishing it.
    if (t + 2 < NT) STAGE((t + 2) % 3, (t + 2) * 32);

    const int buf = t % 3;
    bf16x8 af[8], bv[4];
    #pragma unroll
    for (int mi = 0; mi < 8; mi++)
      af[mi] = *(const bf16x8*)&As[buf][lane >> 4][wr * 128 + mi * 16 + (lane & 15)][0];
    #pragma unroll
    for (int ni = 0; ni < 4; ni++)
      bv[ni] = *(const bf16x8*)&Bs[buf][lane >> 4][wc * 64 + ni * 16 + (lane & 15)][0];
    #pragma unroll
    for (int mi = 0; mi < 8; mi++)
      #pragma unroll
      for (int ni = 0; ni < 4; ni++)
        acc[mi][ni] = __builtin_amdgcn_mfma_f32_16x16x32_bf16(af[mi], bv[ni], acc[mi][ni], 0, 0, 0);
  }

  // C/D layout: col=lane&15, row=(lane>>4)*4+reg (m89-verified).
  #pragma unroll
  for (int mi = 0; mi < 8; mi++)
    #pragma unroll
    for (int ni = 0; ni < 4; ni++)
      #pragma unroll
      for (int r2 = 0; r2 < 4; r2++) {
        const int row = bm + wr * 128 + mi * 16 + (lane >> 4) * 4 + r2;
        const int col = bn + wc * 64 + ni * 16 + (lane & 15);
        C[Cb + (long)row * N + col] = f2bf(acc[mi][ni][r2] * scale);
      }
}

// ---------------------------------------------------------------------------
// Softmax over c (2048) per (b,s) row of S (bf16); wsum[b,c] += softmax row.
// Block = (b, 128-row chunk); wave owns 32 rows, accumulates its 32 c-slots
// in registers; cross-wave LDS reduce; ONE atomicAdd per c per block
// (262K atomics total vs 4.2M in r2).
// ---------------------------------------------------------------------------
__global__ __launch_bounds__(256)
void softmax_wsum(const ushort* __restrict__ S, float* __restrict__ wsum)
{
  const int b = blockIdx.x;
  const int s0 = blockIdx.y * 128;
  const int lane = threadIdx.x & 63;
  const int w = threadIdx.x >> 6;
  __shared__ float red[4][2048];
  const ushort* Sb = S + (((long)b * 1024) + s0 + w * 32) * 2048;

  float acc[32];
  #pragma unroll
  for (int i = 0; i < 32; i++) acc[i] = 0.f;

  for (int r = 0; r < 32; r++) {
    const ushort* row = Sb + (long)r * 2048;
    float v[32];
    #pragma unroll
    for (int i = 0; i < 4; i++) {
      uint4 u = *(const uint4*)(row + i * 512 + lane * 8);
      const ushort* up = (const ushort*)&u;
      #pragma unroll
      for (int j = 0; j < 8; j++) v[i * 8 + j] = bf2f(up[j]);
    }
    float m = v[0];
    #pragma unroll
    for (int i = 1; i < 32; i++) m = fmaxf(m, v[i]);
    #pragma unroll
    for (int o = 1; o < 64; o <<= 1) m = fmaxf(m, __shfl_xor(m, o));
    float ssum = 0.f;
    #pragma unroll
    for (int i = 0; i < 32; i++) { v[i] = __expf(v[i] - m); ssum += v[i]; }
    #pragma unroll
    for (int o = 1; o < 64; o <<= 1) ssum += __shfl_xor(ssum, o);
    const float inv = 1.f / ssum;
    #pragma unroll
    for (int i = 0; i < 32; i++) acc[i] += v[i] * inv;
  }

  #pragma unroll
  for (int i = 0; i < 4; i++)
    #pragma unroll
    for (int j = 0; j < 8; j++)
      red[w][i * 512 + lane * 8 + j] = acc[i * 8 + j];
  __syncthreads();

  float* wb = wsum + b * 2048;
  #pragma unroll
  for (int k = 0; k < 8; k++) {
    const int c = k * 256 + threadIdx.x;
    atomicAdd(&wb[c], red[0][c] + red[1][c] + red[2][c] + red[3][c]);
  }
}

// t[b,d] = sum_c wsum[b,c] * cyc16[b,c,d]
__global__ __launch_bounds__(256)
void wcyc_kernel(const ushort* __restrict__ cyc, const float* __restrict__ wsum,
                 float* __restrict__ t)
{
  const int b = blockIdx.x;
  const int d = blockIdx.y * 256 + threadIdx.x;
  const int c0 = blockIdx.z * 256;
  const ushort* cb = cyc + ((long)b * 2048 + c0) * 1280 + d;
  const float* wb = wsum + b * 2048 + c0;
  float a = 0.f;
  for (int c = 0; c < 256; c++) a += wb[c] * bf2f(cb[(long)c * 1280]);
  atomicAdd(&t[b * 1280 + d], a);
}

// xcat[b, 1280+d] = mean_s sub16[b,s,d]
__global__ __launch_bounds__(256)
void submean_kernel(const ushort* __restrict__ sub, float* __restrict__ xcat)
{
  const int b = blockIdx.x;
  const int d = blockIdx.y * 256 + threadIdx.x;
  const int s0 = blockIdx.z * 256;
  const ushort* sb = sub + ((long)b * 1024 + s0) * 1280 + d;
  float a = 0.f;
  for (int s = 0; s < 256; s++) a += bf2f(sb[(long)s * 1280]);
  atomicAdd(&xcat[b * 2560 + 1280 + d], a * (1.f / 1024.f));
}

// xcat[b, dp] = (1/1024) * sum_d t[b,d] * Wv[d,dp]
__global__ __launch_bounds__(256)
void xv_kernel(const float* __restrict__ t, const float* __restrict__ Wv,
               float* __restrict__ xcat)
{
  const int b = blockIdx.y;
  const int dp = blockIdx.x * 256 + threadIdx.x;
  __shared__ float tl[1280];
  for (int i = threadIdx.x; i < 1280; i += 256) tl[i] = t[b * 1280 + i];
  __syncthreads();
  float a = 0.f;
  for (int d = 0; d < 1280; d++) a += tl[d] * Wv[(long)d * 1280 + dp];
  xcat[b * 2560 + dp] = a * (1.f / 1024.f);
}

// h1 = relu(xcat @ W1 + b1)
__global__ __launch_bounds__(256)
void mlp1_kernel(const float* __restrict__ xcat, const float* __restrict__ W1,
                 const float* __restrict__ b1, float* __restrict__ h1)
{
  const int b = blockIdx.y;
  const int j = blockIdx.x * 256 + threadIdx.x;
  __shared__ float xl[2560];
  for (int i = threadIdx.x; i < 2560; i += 256) xl[i] = xcat[b * 2560 + i];
  __syncthreads();
  float a = b1[j];
  for (int d = 0; d < 2560; d++) a += xl[d] * W1[(long)d * 512 + j];
  h1[b * 512 + j] = fmaxf(a, 0.f);
}

// h2 = relu(h1 @ W2 + b2); out = sigmoid(h2 @ W3 + b3)
__global__ __launch_bounds__(64)
void mlp23_kernel(const float* __restrict__ h1, const float* __restrict__ W2,
                  const float* __restrict__ b2, const float* __restrict__ W3,
                  const float* __restrict__ b3, float* __restrict__ out)
{
  const int b = blockIdx.x;
  const int j = threadIdx.x;  // 64 threads = 1 wave
  __shared__ float hl[512];
  for (int i = j; i < 512; i += 64) hl[i] = h1[b * 512 + i];
  __syncthreads();
  float a = b2[j];
  for (int d = 0; d < 512; d++) a += hl[d] * W2[d * 64 + j];
  a = fmaxf(a, 0.f);
  float p = a * W3[j];
  #pragma unroll
  for (int o = 1; o < 64; o <<= 1) p += __shfl_xor(p, o);
  if (j == 0) out[b] = 1.f / (1.f + __expf(-(p + b3[0])));
}

extern "C" void kernel_launch(void* const* d_in, const int* in_sizes, int n_in,
                              void* d_out, int out_size, void* d_ws, size_t ws_size,
                              hipStream_t stream)
{
  const float* cyclase   = (const float*)d_in[0];
  const float* substrate = (const float*)d_in[1];
  // d_in[2], d_in[3]: masks — reference's masking is a no-op (replicated bug).
  const float* Wq = (const float*)d_in[4];
  const float* Wk = (const float*)d_in[5];
  const float* Wv = (const float*)d_in[6];
  const float* W1 = (const float*)d_in[7];
  const float* b1 = (const float*)d_in[8];
  const float* W2 = (const float*)d_in[9];
  const float* b2 = (const float*)d_in[10];
  const float* W3 = (const float*)d_in[11];
  const float* b3 = (const float*)d_in[12];
  float* out = (float*)d_out;
  (void)in_sizes; (void)n_in; (void)out_size; (void)ws_size;

  // Workspace (lifetime-aliased, ~193.5 MB):
  //   [0, 84M)            cyc16                     (cvt .. wcyc)
  //   [84M, 151.2M)       sub16(42M)+Mkq(3.3M)   -> S(67.1M) after both dead
  //   [151.2M, 193.1M)    Wq16+Wk16(6.6M)        -> T1(42M) after Mkq-gemm
  //   [193.1M, ...)       wsum/tbuf/xcat/h1
  char* ws = (char*)d_ws;
  ushort* cyc16 = (ushort*)ws;
  char*   base2 = ws + 83886080;
  ushort* sub16 = (ushort*)base2;
  ushort* Mkq   = (ushort*)(base2 + 41943040);
  ushort* S     = (ushort*)base2;
  char*   base3 = base2 + 67108864;
  ushort* T1    = (ushort*)base3;
  ushort* Wq16  = (ushort*)base3;
  ushort* Wk16  = (ushort*)(base3 + 3276800);
  char*   base4 = base3 + 41943040;
  float* wsum = (float*)base4;
  float* tbuf = (float*)(base4 + 131072);
  float* xcat = (float*)(base4 + 131072 + 81920);
  float* h1   = (float*)(base4 + 131072 + 81920 + 163840);

  hipMemsetAsync(wsum, 0, 16 * 2048 * 4, stream);
  hipMemsetAsync(tbuf, 0, 16 * 1280 * 4, stream);
  hipMemsetAsync(xcat, 0, 16 * 2560 * 4, stream);

  cvt_bf16<<<200, 256, 0, stream>>>(Wq, Wq16, 1280l * 1280 / 8);
  cvt_bf16<<<200, 256, 0, stream>>>(Wk, Wk16, 1280l * 1280 / 8);
  cvt_bf16<<<2048, 256, 0, stream>>>(substrate, sub16, 16l * 1024 * 1280 / 8);
  cvt_bf16<<<2048, 256, 0, stream>>>(cyclase, cyc16, 16l * 2048 * 1280 / 8);

  // Mkq = Wk @ Wq^T * (1/sqrt(1280))  [1280,1280]
  gemm_ring<false><<<25, 512, 0, stream>>>(Wk16, Wq16, Mkq,
      1280, 1280, 5, 5, 0, 0, 0, 0.02795084971874737f);

  submean_kernel<<<dim3(16, 5, 4), 256, 0, stream>>>(sub16, xcat);

  // T1 = sub16 @ Mkq^T  [16384,1280]  (by-chunks share the A-panel per XCD;
  // Mkq 3.3MB is L2-resident)
  gemm_ring<false><<<320, 512, 0, stream>>>(sub16, Mkq, T1,
      1280, 1280, 5, 64, 0, 0, 0, 1.0f);

  // S[b] = T1[b] @ cyc16[b]^T  [16,1024,2048]
  gemm_ring<true><<<512, 512, 0, stream>>>(T1, cyc16, S,
      1280, 2048, 8, 4, 1024l * 1280, 2048l * 1280, 1024l * 2048, 1.0f);

  softmax_wsum<<<dim3(16, 8), 256, 0, stream>>>(S, wsum);
  wcyc_kernel<<<dim3(16, 5, 8), 256, 0, stream>>>(cyc16, wsum, tbuf);
  xv_kernel<<<dim3(5, 16), 256, 0, stream>>>(tbuf, Wv, xcat);
  mlp1_kernel<<<dim3(2, 16), 256, 0, stream>>>(xcat, W1, b1, h1);
  mlp23_kernel<<<16, 64, 0, stream>>>(h1, W2, b2, W3, b3, out);
}

// Round 4
// 630.539 us; speedup vs baseline: 2.2209x; 1.1419x over previous
//
#include <hip/hip_runtime.h>
#include <hip/hip_bf16.h>

#define DEV static __device__ __forceinline__

typedef __attribute__((ext_vector_type(4))) float f32x4;
typedef __attribute__((ext_vector_type(8))) short bf16x8;

DEV ushort f2bf(float f){
  union { float f; unsigned u; } v; v.f = f;
  return (ushort)((v.u + 0x7FFFu + ((v.u >> 16) & 1u)) >> 16);
}
DEV float bf2f(ushort u){
  union { unsigned u; float f; } v; v.u = ((unsigned)u) << 16;
  return v.f;
}

// async global->LDS, 16B per lane; LDS dest is wave-uniform base + lane*16.
DEV void gload16(const ushort* g, ushort* l) {
  __builtin_amdgcn_global_load_lds(
      (const __attribute__((address_space(1))) unsigned*)g,
      (__attribute__((address_space(3))) unsigned*)l, 16, 0, 0);
}

// ---------------------------------------------------------------------------
// Elementwise f32 -> bf16 (8 elems/thread, grid-stride).
// ---------------------------------------------------------------------------
__global__ __launch_bounds__(256)
void cvt_bf16(const float* __restrict__ src, ushort* __restrict__ dst, long n8)
{
  const long stride = (long)gridDim.x * 256;
  for (long i = (long)blockIdx.x * 256 + threadIdx.x; i < n8; i += stride) {
    const float4 a = *(const float4*)(src + i * 8);
    const float4 b = *(const float4*)(src + i * 8 + 4);
    union { ushort u[8]; uint4 v; } pk;
    pk.u[0] = f2bf(a.x); pk.u[1] = f2bf(a.y); pk.u[2] = f2bf(a.z); pk.u[3] = f2bf(a.w);
    pk.u[4] = f2bf(b.x); pk.u[5] = f2bf(b.y); pk.u[6] = f2bf(b.z); pk.u[7] = f2bf(b.w);
    *(uint4*)(dst + i * 8) = pk.v;
  }
}

// ---------------------------------------------------------------------------
// bf16 GEMM, 8-phase schedule (m201 port): C[M,N] = (A[M,K] @ B^T)*scale,
// B is [N,K] K-contiguous. 256x256 tile, 8 waves (2x4, each 128x64 of C).
// K processed in GROUPS of 32 (2 groups = one 64-K tile; 2 phases/group =
// 8 phases per 128 K). LDS = 4-slot ring of 32KB groups (A 16KB + B 16KB).
// Phase: {ds_read frags for THIS phase, 2x global_load_lds staging group g+2,
//         s_barrier, lgkmcnt(0)+sched_barrier(0), setprio(1), 16 MFMA,
//         setprio(0), barrier}.  Group boundary: s_waitcnt vmcnt(4) — group
// g+1's 4 loads stay in flight; never drains in the main loop (T3+T4).
// B-frags read in phase alpha, reused in beta (zero duplicate LDS reads).
// [kb][row][8] subtiling: linear for the DMA and conflict-free ds_read_b128.
// Requires M%256==0, N%256==0, K%64==0, K/32 >= 2.
// ---------------------------------------------------------------------------
template<bool BY_FAST>
__global__ __launch_bounds__(512, 2)
void gemm8p(const ushort* __restrict__ A, const ushort* __restrict__ B,
            ushort* __restrict__ C, int K, int N, int nbx, int nby,
            long sA, long sB, long sC, float scale)
{
  __shared__ __align__(16) ushort Ag[4][4][256][8];  // 64 KB: ring x kb x row x 8
  __shared__ __align__(16) ushort Bg[4][4][256][8];  // 64 KB

  const int tid = threadIdx.x, lane = tid & 63, wid = tid >> 6;
  const int wr = wid >> 2, wc = wid & 3;  // 2 x 4 waves, each 128x64 of C

  // bijective XCD-chunk swizzle (m204)
  const int nwg = gridDim.x;
  const int q = nwg >> 3, r = nwg & 7;
  const int xcd = blockIdx.x & 7, lid = blockIdx.x >> 3;
  const int id = (xcd < r ? xcd * (q + 1) : r * (q + 1) + (xcd - r) * q) + lid;
  const int per = nbx * nby;
  const int z = id / per, rem = id - z * per;
  const int bx = BY_FAST ? rem / nby : rem % nbx;
  const int by = BY_FAST ? rem % nby : rem / nbx;

  const int bm = by * 256, bn = bx * 256;
  const long Ab = (long)z * sA, Bb = (long)z * sB, Cb = (long)z * sC;

  f32x4 acc[8][4];
  #pragma unroll
  for (int i = 0; i < 8; i++)
    #pragma unroll
    for (int j = 0; j < 4; j++)
      acc[i][j] = (f32x4){0.f, 0.f, 0.f, 0.f};

  // Staging: 16 A-chunks (kb x 64-row-block) + 16 B-chunks of 1KB per group.
  // Wave w owns chunks {2w, 2w+1}: kb = c>>2, rb = c&3. Per-thread global
  // pointers precomputed; k-advance = +32 elements per group.
  const int c0 = wid * 2, c1 = wid * 2 + 1;
  const int kb0 = c0 >> 2, rb0 = c0 & 3, kb1 = c1 >> 2, rb1 = c1 & 3;
  const ushort* ag0 = A + Ab + (long)(bm + rb0 * 64 + lane) * K + kb0 * 8;
  const ushort* ag1 = A + Ab + (long)(bm + rb1 * 64 + lane) * K + kb1 * 8;
  const ushort* bg0 = B + Bb + (long)(bn + rb0 * 64 + lane) * K + kb0 * 8;
  const ushort* bg1 = B + Bb + (long)(bn + rb1 * 64 + lane) * K + kb1 * 8;

  auto STAGE_A = [&](int g) {
    const int rg = g & 3;
    gload16(ag0 + g * 32, &Ag[rg][kb0][rb0 * 64][0]);
    gload16(ag1 + g * 32, &Ag[rg][kb1][rb1 * 64][0]);
  };
  auto STAGE_B = [&](int g) {
    const int rg = g & 3;
    gload16(bg0 + g * 32, &Bg[rg][kb0][rb0 * 64][0]);
    gload16(bg1 + g * 32, &Bg[rg][kb1][rb1 * 64][0]);
  };

  const int NG = K >> 5;  // 32-K groups; >= 2 required
  STAGE_A(0); STAGE_B(0); STAGE_A(1); STAGE_B(1);
  asm volatile("s_waitcnt vmcnt(4)" ::: "memory");  // group 0 landed; g1 in flight
  __builtin_amdgcn_s_barrier();

  const int lkb = lane >> 4, lrow = lane & 15;
  bf16x8 bv[4];

  for (int g = 0; g < NG; ++g) {
    const int rg = g & 3;
    // ---------------- phase alpha: mh=0 (acc rows 0..63 of wave tile) -------
    bf16x8 av[4];
    #pragma unroll
    for (int mi = 0; mi < 4; mi++)
      av[mi] = *(const bf16x8*)&Ag[rg][lkb][wr * 128 + mi * 16 + lrow][0];
    #pragma unroll
    for (int ni = 0; ni < 4; ni++)
      bv[ni] = *(const bf16x8*)&Bg[rg][lkb][wc * 64 + ni * 16 + lrow][0];
    if (g + 2 < NG) STAGE_A(g + 2);
    __builtin_amdgcn_s_barrier();
    asm volatile("s_waitcnt lgkmcnt(0)" ::: "memory");
    __builtin_amdgcn_sched_barrier(0);          // rule #18: pin MFMA after wait
    __builtin_amdgcn_s_setprio(1);
    #pragma unroll
    for (int mi = 0; mi < 4; mi++)
      #pragma unroll
      for (int ni = 0; ni < 4; ni++)
        acc[mi][ni] = __builtin_amdgcn_mfma_f32_16x16x32_bf16(av[mi], bv[ni], acc[mi][ni], 0, 0, 0);
    __builtin_amdgcn_s_setprio(0);
    __builtin_amdgcn_s_barrier();
    // ---------------- phase beta: mh=1 (acc rows 64..127), B reused ---------
    #pragma unroll
    for (int mi = 0; mi < 4; mi++)
      av[mi] = *(const bf16x8*)&Ag[rg][lkb][wr * 128 + (mi + 4) * 16 + lrow][0];
    if (g + 2 < NG) STAGE_B(g + 2);
    __builtin_amdgcn_s_barrier();
    asm volatile("s_waitcnt lgkmcnt(0)" ::: "memory");
    __builtin_amdgcn_sched_barrier(0);
    __builtin_amdgcn_s_setprio(1);
    #pragma unroll
    for (int mi = 0; mi < 4; mi++)
      #pragma unroll
      for (int ni = 0; ni < 4; ni++)
        acc[mi + 4][ni] = __builtin_amdgcn_mfma_f32_16x16x32_bf16(av[mi], bv[ni], acc[mi + 4][ni], 0, 0, 0);
    __builtin_amdgcn_s_setprio(0);
    // group boundary: ensure group g+1 landed for everyone after the barrier,
    // keeping group g+2's 4 loads in flight (counted, never drains mid-loop).
    if (g + 2 < NG)      asm volatile("s_waitcnt vmcnt(4)" ::: "memory");
    else if (g + 1 < NG) asm volatile("s_waitcnt vmcnt(0)" ::: "memory");
    __builtin_amdgcn_s_barrier();
  }

  // C/D layout: col=lane&15, row=(lane>>4)*4+reg (m89-verified).
  #pragma unroll
  for (int mi = 0; mi < 8; mi++)
    #pragma unroll
    for (int ni = 0; ni < 4; ni++)
      #pragma unroll
      for (int r2 = 0; r2 < 4; r2++) {
        const int row = bm + wr * 128 + mi * 16 + (lane >> 4) * 4 + r2;
        const int col = bn + wc * 64 + ni * 16 + (lane & 15);
        C[Cb + (long)row * N + col] = f2bf(acc[mi][ni][r2] * scale);
      }
}

// ---------------------------------------------------------------------------
// Softmax over c (2048) per (b,s) row of S (bf16); wsum[b,c] += softmax row.
// Wave owns 32 rows in regs; cross-wave LDS reduce; one atomicAdd/c/block.
// ---------------------------------------------------------------------------
__global__ __launch_bounds__(256)
void softmax_wsum(const ushort* __restrict__ S, float* __restrict__ wsum)
{
  const int b = blockIdx.x;
  const int s0 = blockIdx.y * 128;
  const int lane = threadIdx.x & 63;
  const int w = threadIdx.x >> 6;
  __shared__ float red[4][2048];
  const ushort* Sb = S + (((long)b * 1024) + s0 + w * 32) * 2048;

  float acc[32];
  #pragma unroll
  for (int i = 0; i < 32; i++) acc[i] = 0.f;

  for (int r = 0; r < 32; r++) {
    const ushort* row = Sb + (long)r * 2048;
    float v[32];
    #pragma unroll
    for (int i = 0; i < 4; i++) {
      uint4 u = *(const uint4*)(row + i * 512 + lane * 8);
      const ushort* up = (const ushort*)&u;
      #pragma unroll
      for (int j = 0; j < 8; j++) v[i * 8 + j] = bf2f(up[j]);
    }
    float m = v[0];
    #pragma unroll
    for (int i = 1; i < 32; i++) m = fmaxf(m, v[i]);
    #pragma unroll
    for (int o = 1; o < 64; o <<= 1) m = fmaxf(m, __shfl_xor(m, o));
    float ssum = 0.f;
    #pragma unroll
    for (int i = 0; i < 32; i++) { v[i] = __expf(v[i] - m); ssum += v[i]; }
    #pragma unroll
    for (int o = 1; o < 64; o <<= 1) ssum += __shfl_xor(ssum, o);
    const float inv = 1.f / ssum;
    #pragma unroll
    for (int i = 0; i < 32; i++) acc[i] += v[i] * inv;
  }

  #pragma unroll
  for (int i = 0; i < 4; i++)
    #pragma unroll
    for (int j = 0; j < 8; j++)
      red[w][i * 512 + lane * 8 + j] = acc[i * 8 + j];
  __syncthreads();

  float* wb = wsum + b * 2048;
  #pragma unroll
  for (int k = 0; k < 8; k++) {
    const int c = k * 256 + threadIdx.x;
    atomicAdd(&wb[c], red[0][c] + red[1][c] + red[2][c] + red[3][c]);
  }
}

// t[b,d] = sum_c wsum[b,c] * cyc16[b,c,d]
__global__ __launch_bounds__(256)
void wcyc_kernel(const ushort* __restrict__ cyc, const float* __restrict__ wsum,
                 float* __restrict__ t)
{
  const int b = blockIdx.x;
  const int d = blockIdx.y * 256 + threadIdx.x;
  const int c0 = blockIdx.z * 256;
  const ushort* cb = cyc + ((long)b * 2048 + c0) * 1280 + d;
  const float* wb = wsum + b * 2048 + c0;
  float a = 0.f;
  for (int c = 0; c < 256; c++) a += wb[c] * bf2f(cb[(long)c * 1280]);
  atomicAdd(&t[b * 1280 + d], a);
}

// xcat[b, 1280+d] = mean_s sub16[b,s,d]
__global__ __launch_bounds__(256)
void submean_kernel(const ushort* __restrict__ sub, float* __restrict__ xcat)
{
  const int b = blockIdx.x;
  const int d = blockIdx.y * 256 + threadIdx.x;
  const int s0 = blockIdx.z * 256;
  const ushort* sb = sub + ((long)b * 1024 + s0) * 1280 + d;
  float a = 0.f;
  for (int s = 0; s < 256; s++) a += bf2f(sb[(long)s * 1280]);
  atomicAdd(&xcat[b * 2560 + 1280 + d], a * (1.f / 1024.f));
}

// xcat[b, dp] = (1/1024) * sum_d t[b,d] * Wv[d,dp]
__global__ __launch_bounds__(256)
void xv_kernel(const float* __restrict__ t, const float* __restrict__ Wv,
               float* __restrict__ xcat)
{
  const int b = blockIdx.y;
  const int dp = blockIdx.x * 256 + threadIdx.x;
  __shared__ float tl[1280];
  for (int i = threadIdx.x; i < 1280; i += 256) tl[i] = t[b * 1280 + i];
  __syncthreads();
  float a = 0.f;
  for (int d = 0; d < 1280; d++) a += tl[d] * Wv[(long)d * 1280 + dp];
  xcat[b * 2560 + dp] = a * (1.f / 1024.f);
}

// h1 = relu(xcat @ W1 + b1)
__global__ __launch_bounds__(256)
void mlp1_kernel(const float* __restrict__ xcat, const float* __restrict__ W1,
                 const float* __restrict__ b1, float* __restrict__ h1)
{
  const int b = blockIdx.y;
  const int j = blockIdx.x * 256 + threadIdx.x;
  __shared__ float xl[2560];
  for (int i = threadIdx.x; i < 2560; i += 256) xl[i] = xcat[b * 2560 + i];
  __syncthreads();
  float a = b1[j];
  for (int d = 0; d < 2560; d++) a += xl[d] * W1[(long)d * 512 + j];
  h1[b * 512 + j] = fmaxf(a, 0.f);
}

// h2 = relu(h1 @ W2 + b2); out = sigmoid(h2 @ W3 + b3)
__global__ __launch_bounds__(64)
void mlp23_kernel(const float* __restrict__ h1, const float* __restrict__ W2,
                  const float* __restrict__ b2, const float* __restrict__ W3,
                  const float* __restrict__ b3, float* __restrict__ out)
{
  const int b = blockIdx.x;
  const int j = threadIdx.x;  // 64 threads = 1 wave
  __shared__ float hl[512];
  for (int i = j; i < 512; i += 64) hl[i] = h1[b * 512 + i];
  __syncthreads();
  float a = b2[j];
  for (int d = 0; d < 512; d++) a += hl[d] * W2[d * 64 + j];
  a = fmaxf(a, 0.f);
  float p = a * W3[j];
  #pragma unroll
  for (int o = 1; o < 64; o <<= 1) p += __shfl_xor(p, o);
  if (j == 0) out[b] = 1.f / (1.f + __expf(-(p + b3[0])));
}

extern "C" void kernel_launch(void* const* d_in, const int* in_sizes, int n_in,
                              void* d_out, int out_size, void* d_ws, size_t ws_size,
                              hipStream_t stream)
{
  const float* cyclase   = (const float*)d_in[0];
  const float* substrate = (const float*)d_in[1];
  // d_in[2], d_in[3]: masks — reference's masking is a no-op (replicated bug).
  const float* Wq = (const float*)d_in[4];
  const float* Wk = (const float*)d_in[5];
  const float* Wv = (const float*)d_in[6];
  const float* W1 = (const float*)d_in[7];
  const float* b1 = (const float*)d_in[8];
  const float* W2 = (const float*)d_in[9];
  const float* b2 = (const float*)d_in[10];
  const float* W3 = (const float*)d_in[11];
  const float* b3 = (const float*)d_in[12];
  float* out = (float*)d_out;
  (void)in_sizes; (void)n_in; (void)out_size; (void)ws_size;

  // Workspace (lifetime-aliased, ~193.5 MB):
  //   [0, 84M)            cyc16                     (cvt .. wcyc)
  //   [84M, 151.2M)       sub16(42M)+Mkq(3.3M)   -> S(67.1M) after both dead
  //   [151.2M, 193.1M)    Wq16+Wk16(6.6M)        -> T1(42M) after Mkq-gemm
  //   [193.1M, ...)       wsum/tbuf/xcat/h1
  char* ws = (char*)d_ws;
  ushort* cyc16 = (ushort*)ws;
  char*   base2 = ws + 83886080;
  ushort* sub16 = (ushort*)base2;
  ushort* Mkq   = (ushort*)(base2 + 41943040);
  ushort* S     = (ushort*)base2;
  char*   base3 = base2 + 67108864;
  ushort* T1    = (ushort*)base3;
  ushort* Wq16  = (ushort*)base3;
  ushort* Wk16  = (ushort*)(base3 + 3276800);
  char*   base4 = base3 + 41943040;
  float* wsum = (float*)base4;
  float* tbuf = (float*)(base4 + 131072);
  float* xcat = (float*)(base4 + 131072 + 81920);
  float* h1   = (float*)(base4 + 131072 + 81920 + 163840);

  hipMemsetAsync(wsum, 0, 16 * 2048 * 4, stream);
  hipMemsetAsync(tbuf, 0, 16 * 1280 * 4, stream);
  hipMemsetAsync(xcat, 0, 16 * 2560 * 4, stream);

  cvt_bf16<<<200, 256, 0, stream>>>(Wq, Wq16, 1280l * 1280 / 8);
  cvt_bf16<<<200, 256, 0, stream>>>(Wk, Wk16, 1280l * 1280 / 8);
  cvt_bf16<<<2048, 256, 0, stream>>>(substrate, sub16, 16l * 1024 * 1280 / 8);
  cvt_bf16<<<2048, 256, 0, stream>>>(cyclase, cyc16, 16l * 2048 * 1280 / 8);

  // Mkq = Wk @ Wq^T * (1/sqrt(1280))  [1280,1280]
  gemm8p<false><<<25, 512, 0, stream>>>(Wk16, Wq16, Mkq,
      1280, 1280, 5, 5, 0, 0, 0, 0.02795084971874737f);

  submean_kernel<<<dim3(16, 5, 4), 256, 0, stream>>>(sub16, xcat);

  // T1 = sub16 @ Mkq^T  [16384,1280]  (bx-fast: A-panel hot, Mkq L2-resident)
  gemm8p<false><<<320, 512, 0, stream>>>(sub16, Mkq, T1,
      1280, 1280, 5, 64, 0, 0, 0, 1.0f);

  // S[b] = T1[b] @ cyc16[b]^T  [16,1024,2048]  (by-fast: T1[b] L2-resident)
  gemm8p<true><<<512, 512, 0, stream>>>(T1, cyc16, S,
      1280, 2048, 8, 4, 1024l * 1280, 2048l * 1280, 1024l * 2048, 1.0f);

  softmax_wsum<<<dim3(16, 8), 256, 0, stream>>>(S, wsum);
  wcyc_kernel<<<dim3(16, 5, 8), 256, 0, stream>>>(cyc16, wsum, tbuf);
  xv_kernel<<<dim3(5, 16), 256, 0, stream>>>(tbuf, Wv, xcat);
  mlp1_kernel<<<dim3(2, 16), 256, 0, stream>>>(xcat, W1, b1, h1);
  mlp23_kernel<<<16, 64, 0, stream>>>(h1, W2, b2, W3, b3, out);
}